// Round 11
// baseline (795.553 us; speedup 1.0000x reference)
//
#include <hip/hip_runtime.h>

// Fused OT Sinkhorn, MI355X — round 11: kill the bf16 unpacks.
// Round-10 counters: 82% VALU-busy on the 8 active CUs; ~45% of VALU inst
// were bf16 unpack (lshl/and). Fixes:
//  (1) phase B: v_dot2_f32_bf16 consumes packed bf16 pairs directly from the
//      LDS words (9 dot2 + 1 fma per row vs 9 pk_fma + 18 unpack).
//  (2) phase A: coefficient streams stored as f32 (kx4 + ky4 uint4 streams,
//      34B/entry, L2-resident) -> 2 pk_mul + 8 pk_fma per entry, no unpack.

#define N_IMG   8
#define N_PTS   1024
#define OUT_D   128
#define N_CELLS (OUT_D * OUT_D)
#define WIN     11
#define RT      5
#define WINX    18
#define N_TILE  1024            // 32x32 tiles of 4x4 cells
#define N_CHUNK 16
#define CAPE    32768           // stream entries per image (slack; ~15K used)
#define EPS     1e-16f
#define INV_N   (1.0f / 1024.0f)
#define N_ITERS 100

typedef unsigned int   uint_t;
typedef unsigned short u16;
typedef float v2f __attribute__((ext_vector_type(2)));

__device__ __forceinline__ u16 f2bf(float f) {      // RNE f32->bf16
    uint_t b = __float_as_uint(f);
    b += 0x7FFFu + ((b >> 16) & 1u);
    return (u16)(b >> 16);
}
__device__ __forceinline__ float bf2f(u16 h)   { return __uint_as_float(((uint_t)h) << 16); }
__device__ __forceinline__ uint_t cvt_pk_bf16(float lo, float hi) {
    uint_t r;
    asm volatile("v_cvt_pk_bf16_f32 %0, %1, %2" : "=v"(r) : "v"(lo), "v"(hi));
    return r;
}
__device__ __forceinline__ float dot2bf(uint_t a, uint_t b, float c) {
    float r;
    asm volatile("v_dot2_f32_bf16 %0, %1, %2, %3" : "=v"(r) : "v"(a), "v"(b), "v"(c));
    return r;
}

// ---------------------------------------------------------------- builder --
// One WG per image. Deterministic entry positions (no heavy atomics):
// tile list order = (iy0 asc, ix0 asc, pid asc) via row-prefix table P.
__global__ __launch_bounds__(1024) void ot_build(
    const float* __restrict__ pts, uint4* __restrict__ kxs,
    uint4* __restrict__ kys, u16* __restrict__ pstream,
    u16* __restrict__ tileofg, uint_t* __restrict__ cbaseg,
    uint_t* __restrict__ cleng)
{
    __shared__ uint_t chist[N_CELLS];      // 64KB
    __shared__ u16    P[128 * 129];        // 33KB  P[r][c] = #pts row r, ix0 < c
    __shared__ u16    c0tab[N_PTS];
    __shared__ u16    tslot[N_TILE];
    __shared__ u16    tlen[N_TILE];
    __shared__ u16    tof[N_TILE];
    __shared__ uint_t bins[1025];
    __shared__ uint_t cbase_l[N_CHUNK + 1];

    const int img = blockIdx.x, tid = threadIdx.x;
    for (int i = tid; i < N_CELLS; i += 1024) chist[i] = 0;
    for (int i = tid; i < 1025;    i += 1024) bins[i] = 0;
    __syncthreads();

    const float x = pts[(img * N_PTS + tid) * 2 + 0];
    const float y = pts[(img * N_PTS + tid) * 2 + 1];
    const int nx = (int)floorf((x - 2.f) * 0.25f + 0.5f);
    const int ny = (int)floorf((y - 2.f) * 0.25f + 0.5f);
    const int ix0 = min(max(nx - RT, 0), OUT_D - WIN);
    const int iy0 = min(max(ny - RT, 0), OUT_D - WIN);
    const float xx = x * x, yy = y * y;
    float kx[WIN], ky[WIN];
#pragma unroll
    for (int k = 0; k < WIN; ++k) {        // mimic reference's x^2-2xc+c^2
        float cx = (float)(4 * (ix0 + k) + 2);
        kx[k] = __expf(-((xx - 2.f * x * cx) + cx * cx) * 0.1f);
        float cy = (float)(4 * (iy0 + k) + 2);
        ky[k] = __expf(-((yy - 2.f * y * cy) + cy * cy) * 0.1f);
    }
    const int cell0 = (iy0 << 7) | ix0;
    c0tab[tid] = (u16)cell0;
    atomicAdd(&chist[cell0], 1u);
    __syncthreads();

    if (tid < 128) {
        uint_t acc = 0;
        P[tid * 129 + 0] = 0;
        for (int c = 0; c < 128; ++c) { acc += chist[(tid << 7) + c]; P[tid * 129 + c + 1] = (u16)acc; }
    }
    __syncthreads();

    int rank = 0;                          // among same-(iy0,ix0), by pid
    for (int p = 0; p < N_PTS; ++p) rank += (p < tid && c0tab[p] == (u16)cell0) ? 1 : 0;

    // tile lengths (thread = tile) + length histogram
    {
        int ty = tid >> 5, tx = tid & 31;
        int rlo = max(4 * ty - 10, 0), rhi = min(4 * ty + 3, OUT_D - WIN);
        int xlo = max(4 * tx - 10, 0), xhi = min(4 * tx + 3, OUT_D - WIN);
        uint_t len = 0;
        for (int r = rlo; r <= rhi; ++r)
            len += (uint_t)P[r * 129 + xhi + 1] - (uint_t)P[r * 129 + xlo];
        tlen[tid] = (u16)len;
        atomicAdd(&bins[len], 1u);
    }
    __syncthreads();
    if (tid == 0) {                        // descending-length start offsets
        uint_t acc = 0;
        for (int L = 1024; L >= 0; --L) { uint_t t = bins[L]; bins[L] = acc; acc += t; }
    }
    __syncthreads();
    {
        uint_t slot = atomicAdd(&bins[tlen[tid]], 1u);
        tslot[tid] = (u16)slot;
        tof[slot] = (u16)tid;
    }
    __syncthreads();
    if (tid < N_CHUNK) cbase_l[tid] = tlen[tof[tid * 64]];   // chunk maxlen
    __syncthreads();
    if (tid == 0) {
        uint_t acc = 0;
        for (int c = 0; c < N_CHUNK; ++c) { uint_t l = cbase_l[c]; cbase_l[c] = acc; acc += l * 64u; }
        cbase_l[N_CHUNK] = acc;
    }
    __syncthreads();
    tileofg[img * N_TILE + tid] = tof[tid];
    if (tid < N_CHUNK) {
        cbaseg[img * N_CHUNK + tid] = cbase_l[tid];
        cleng[img * N_CHUNK + tid]  = tlen[tof[tid * 64]];
    }

    // fill streams (f32 coefficients)
    uint4* kxb = kxs + (size_t)img * CAPE;
    uint4* kyb = kys + (size_t)img * CAPE;
    u16*   ps  = pstream + (size_t)img * CAPE;
    const int tya = iy0 >> 2, tyb2 = (iy0 + 10) >> 2;
    const int txa = ix0 >> 2, txb2 = (ix0 + 10) >> 2;
    for (int ty = tya; ty <= tyb2; ++ty) {
        for (int tx = txa; tx <= txb2; ++tx) {
            int ti = (ty << 5) | tx;
            int slot = tslot[ti];
            int xlo = max(4 * tx - 10, 0), xhi = min(4 * tx + 3, OUT_D - WIN);
            int rlo = max(4 * ty - 10, 0);
            uint_t idx = (uint_t)rank + (uint_t)P[iy0 * 129 + ix0] - (uint_t)P[iy0 * 129 + xlo];
            for (int r = rlo; r < iy0; ++r)
                idx += (uint_t)P[r * 129 + xhi + 1] - (uint_t)P[r * 129 + xlo];
            uint_t eofs = cbase_l[slot >> 6] + idx * 64u + (uint_t)(slot & 63);
            if (eofs < CAPE) {
                float4 kxv, kyv;
#pragma unroll
                for (int c = 0; c < 4; ++c) {
                    int dk = 4 * tx + c - ix0;
                    ((float*)&kxv)[c] = ((unsigned)dk < 11u) ? kx[dk] : 0.f;
                    int dj = 4 * ty + c - iy0;
                    ((float*)&kyv)[c] = ((unsigned)dj < 11u) ? ky[dj] : 0.f;
                }
                kxb[eofs] = *(uint4*)&kxv;
                kyb[eofs] = *(uint4*)&kyv;
                ps[eofs]  = (u16)tid;
            }
        }
    }
}

// ------------------------------------------------------------ main kernel --
__device__ __forceinline__ float blk_sum(float v, volatile float* red)
{
#pragma unroll
    for (int o = 32; o; o >>= 1) v += __shfl_xor(v, o, 64);
    int wave = threadIdx.x >> 6, lane = threadIdx.x & 63;
    if (lane == 0) red[wave] = v;
    __syncthreads();
    if (threadIdx.x < 64) {
        float t = (lane < 16) ? red[lane] : 0.0f;
#pragma unroll
        for (int o = 8; o; o >>= 1) t += __shfl_xor(t, o, 64);
        if (lane == 0) red[0] = t;
    }
    __syncthreads();
    float r = red[0];
    __syncthreads();
    return r;
}

__global__ __launch_bounds__(1024) void ot_fused(
    const float* __restrict__ nd, const float* __restrict__ und,
    const float* __restrict__ pts, const uint4* __restrict__ kxs,
    const uint4* __restrict__ kys, const u16* __restrict__ pstream,
    const u16* __restrict__ tileofg, const uint_t* __restrict__ cbaseg,
    const uint_t* __restrict__ cleng, float* __restrict__ parts)
{
    __shared__ __align__(16) u16 Vh[N_CELLS + 32]; // 32KB bf16 v + zero-mul pad
    __shared__ float  su[N_PTS];                   // 4KB
    __shared__ u16    bktab[N_PTS];                // point -> bank group
    __shared__ u16    sorted_pt[N_PTS];            // deal: slot -> pid
    __shared__ u16    leftover[N_PTS];             // leftover rank -> pid
    __shared__ uint_t ng[8];                       // bucket counts
    __shared__ uint_t og[8];                       // overfull prefix
    __shared__ uint_t cbase_l[N_CHUNK];
    __shared__ uint_t clen_l[N_CHUNK];
    __shared__ float  red[64];

    const int img = blockIdx.x, tid = threadIdx.x;
    const int w = tid >> 6, lane = tid & 63;
    const float* ndi = nd + img * N_CELLS;

    if (tid < N_CHUNK) { cbase_l[tid] = cbaseg[img * N_CHUNK + tid]; clen_l[tid] = cleng[img * N_CHUNK + tid]; }
    if (tid < 32) Vh[N_CELLS + tid] = 0;
    if (tid < 8)  ng[tid] = 0;
    su[tid] = INV_N;
    __syncthreads();

    // ---- exact cluster-aligned deal (bf16 bank geometry) ------------------
    {
        float x_ = pts[(img * N_PTS + tid) * 2 + 0];
        int nx_ = (int)floorf((x_ - 2.f) * 0.25f + 0.5f);
        int i0_ = min(max(nx_ - RT, 0), OUT_D - WIN);
        bktab[tid] = (u16)(((i0_ & ~7) >> 3) & 7);
    }
    __syncthreads();
    {
        const int g = (int)bktab[tid];
        int rnk = 0;                       // deterministic rank by pid
        for (int p = 0; p < tid; ++p) rnk += ((int)bktab[p] == g) ? 1 : 0;
        atomicAdd(&ng[g], 1u);
        __syncthreads();
        if (tid == 0) {
            uint_t acc = 0;
            for (int b = 0; b < 8; ++b) { og[b] = acc; acc += (ng[b] > 128u) ? ng[b] - 128u : 0u; }
        }
        __syncthreads();
        if (rnk < 128) sorted_pt[rnk * 8 + g] = (u16)tid;        // cluster rnk, slot g
        else           leftover[og[g] + (uint_t)(rnk - 128)] = (u16)tid;
        __syncthreads();
        const int c = tid >> 3, j = tid & 7;                     // my slot
        if (c >= (int)ng[j]) {             // empty slot -> take E-th leftover
            int E = 0;
#pragma unroll
            for (int j2 = 0; j2 < 8; ++j2) {
                int nj = (int)ng[j2];
                E += max(0, c - nj) + ((j2 < j && c >= nj) ? 1 : 0);
            }
            sorted_pt[tid] = leftover[E];
        }
    }
    __syncthreads();
    const int pp = (int)sorted_pt[tid];    // my point (cluster-bank-tiled)

    // ---- phase-A ownership: thread owns one 4x4 tile (slot = w*64+lane) ---
    const int tile = (int)tileofg[img * N_TILE + w * 64 + lane];
    const int ty4 = (tile >> 5) * 4, tx4 = (tile & 31) * 4;
    float4 b4[4];
#pragma unroll
    for (int r = 0; r < 4; ++r) b4[r] = *(const float4*)(ndi + (ty4 + r) * OUT_D + tx4);
    const uint4* kxsb = kxs + (size_t)img * CAPE + cbase_l[w] + lane;
    const uint4* kysb = kys + (size_t)img * CAPE + cbase_l[w] + lane;
    const u16*   psb  = pstream + (size_t)img * CAPE + cbase_l[w] + lane;
    const int    alen = (int)clen_l[w];               // wave-uniform

    // ---- phase-B per-point data (thread = point pp) -----------------------
    const float x = pts[(img * N_PTS + pp) * 2 + 0];
    const float y = pts[(img * N_PTS + pp) * 2 + 1];
    const int nx = (int)floorf((x - 2.f) * 0.25f + 0.5f);
    const int ny = (int)floorf((y - 2.f) * 0.25f + 0.5f);
    const int ix0 = min(max(nx - RT, 0), OUT_D - WIN);
    const int iy0 = min(max(ny - RT, 0), OUT_D - WIN);
    const int ixq = ix0 & ~7;                          // 16B-aligned bf16 window
    const float xx = x * x, yy = y * y;
    uint_t kxp[WINX / 2];                              // 9 packed bf16 pairs
    float  kyr[WIN];
#pragma unroll
    for (int q = 0; q < WINX / 2; ++q) {
        float kv[2];
#pragma unroll
        for (int h = 0; h < 2; ++h) {
            int col = ixq + 2 * q + h, dk = col - ix0;
            float cx = (float)(4 * col + 2);
            kv[h] = ((unsigned)dk < 11u) ? __expf(-((xx - 2.f * x * cx) + cx * cx) * 0.1f) : 0.f;
        }
        kxp[q] = cvt_pk_bf16(kv[0], kv[1]);
    }
#pragma unroll
    for (int j = 0; j < WIN; ++j) {
        float cy = (float)(4 * (iy0 + j) + 2);
        kyr[j] = __expf(-((yy - 2.f * y * cy) + cy * cy) * 0.1f);
    }
    float ureg = INV_N;
    const u16* vbp = &Vh[iy0 * OUT_D + ixq];

    // ---- Sinkhorn main loop ----------------------------------------------
    for (int it = 0; it < N_ITERS; ++it) {
        // phase A: 4x4-tile gather, prefetch-1, f32 coeffs (no unpack)
        v2f acc2[8] = {};
        uint4 cx4 = make_uint4(0u,0u,0u,0u), cy4 = make_uint4(0u,0u,0u,0u);
        u16 pid = 0;
        if (alen > 0) { cx4 = kxsb[0]; cy4 = kysb[0]; pid = psb[0]; }
        for (int t = 1; t <= alen; ++t) {
            uint4 nx4 = kxsb[(size_t)t * 64];         // prefetch next entry
            uint4 ny4 = kysb[(size_t)t * 64];
            u16   pn  = psb[(size_t)t * 64];
            float uv = su[pid & 1023u];
            v2f kxa = {__uint_as_float(cx4.x), __uint_as_float(cx4.y)};
            v2f kxb2= {__uint_as_float(cx4.z), __uint_as_float(cx4.w)};
            v2f uv2 = {uv, uv};
            v2f kya = {__uint_as_float(cy4.x), __uint_as_float(cy4.y)};
            v2f kyb2= {__uint_as_float(cy4.z), __uint_as_float(cy4.w)};
            v2f s01 = uv2 * kya;                      // {uv*ky0, uv*ky1}
            v2f s23 = uv2 * kyb2;
            acc2[0] += (v2f){s01.x, s01.x} * kxa;  acc2[1] += (v2f){s01.x, s01.x} * kxb2;
            acc2[2] += (v2f){s01.y, s01.y} * kxa;  acc2[3] += (v2f){s01.y, s01.y} * kxb2;
            acc2[4] += (v2f){s23.x, s23.x} * kxa;  acc2[5] += (v2f){s23.x, s23.x} * kxb2;
            acc2[6] += (v2f){s23.y, s23.y} * kxa;  acc2[7] += (v2f){s23.y, s23.y} * kxb2;
            cx4 = nx4; cy4 = ny4; pid = pn;
        }
#pragma unroll
        for (int r = 0; r < 4; ++r) {                 // v = b*rcp(S+eps), pack
            float v0 = b4[r].x * __builtin_amdgcn_rcpf(acc2[2 * r][0] + EPS);
            float v1 = b4[r].y * __builtin_amdgcn_rcpf(acc2[2 * r][1] + EPS);
            float v2 = b4[r].z * __builtin_amdgcn_rcpf(acc2[2 * r + 1][0] + EPS);
            float v3 = b4[r].w * __builtin_amdgcn_rcpf(acc2[2 * r + 1][1] + EPS);
            uint2 wv = make_uint2(cvt_pk_bf16(v0, v1), cvt_pk_bf16(v2, v3));
            *(uint2*)&Vh[(ty4 + r) * OUT_D + tx4] = wv;   // 8B, 8B-aligned
        }
        __syncthreads();

        // phase B: 18-wide bf16 rows, 2x b128 + 1x b32, 9 dot2 per row
        float tt = 0.f;
#pragma unroll
        for (int j = 0; j < WIN; ++j) {
            const u16* row = vbp + j * OUT_D;
            uint4 w0 = *(const uint4*)(row);          // cols 0..7
            uint4 w1 = *(const uint4*)(row + 8);      // cols 8..15
            uint_t w2 = *(const uint_t*)(row + 16);   // cols 16..17
            float rs0, rs1;                           // 2 chains
            rs0 = dot2bf(kxp[0], w0.x, 0.f);
            rs1 = dot2bf(kxp[1], w0.y, 0.f);
            rs0 = dot2bf(kxp[2], w0.z, rs0);
            rs1 = dot2bf(kxp[3], w0.w, rs1);
            rs0 = dot2bf(kxp[4], w1.x, rs0);
            rs1 = dot2bf(kxp[5], w1.y, rs1);
            rs0 = dot2bf(kxp[6], w1.z, rs0);
            rs1 = dot2bf(kxp[7], w1.w, rs1);
            rs0 = dot2bf(kxp[8], w2,   rs0);
            tt = fmaf(kyr[j], rs0 + rs1, tt);
        }
        ureg = INV_N / (tt + EPS);
        su[pp] = ureg;
        __syncthreads();
    }

    // ---- epilogue ---------------------------------------------------------
    const float* sdi = und + img * N_CELLS;
    float sc = 0.f, T = 0.f, ot = 0.f;
#pragma unroll
    for (int r = 0; r < 16; ++r) {
        int c = r * 1024 + tid;
        float beta = 10.0f * logf(bf2f(Vh[c]) + EPS);
        float s = sdi[c];
        sc += s;
        T  = fmaf(s, beta, T);
        ot = fmaf(ndi[c], beta, ot);
    }
    sc = blk_sum(sc, red);
    T  = blk_sum(T,  red);
    ot = blk_sum(ot, red);
    float denom = sc * sc + 1e-8f;
    float c1 = sc / denom, c2 = T / denom;

    float loss = 0.f;
#pragma unroll
    for (int r = 0; r < 16; ++r) {
        int c = r * 1024 + tid;
        float beta = 10.0f * logf(bf2f(Vh[c]) + EPS);
        loss = fmaf(sdi[c], fmaf(c1, beta, -c2), loss);
    }
    loss = blk_sum(loss, red);

    // wd = u_n * sum_window (dy+dx)*Ky*Kx*v (18-tap x-window, kx=0 off-window)
    float wd = 0.f;
#pragma unroll
    for (int j = 0; j < WIN; ++j) {
        float cy = (float)(4 * (iy0 + j) + 2);
        float dy = (yy - 2.f * y * cy) + cy * cy;
        const u16* row = vbp + j * OUT_D;
        float skv = 0.f, sdkv = 0.f;
#pragma unroll
        for (int d = 0; d < WINX; ++d) {
            int col = ixq + d, dk = col - ix0;
            float cx = (float)(4 * col + 2);
            float kxv = ((unsigned)dk < 11u) ? __expf(-((xx - 2.f * x * cx) + cx * cx) * 0.1f) : 0.f;
            float dx = (xx - 2.f * x * cx) + cx * cx;
            float kv = kxv * bf2f(row[d]);
            skv += kv;
            sdkv = fmaf(dx, kv, sdkv);
        }
        wd = fmaf(kyr[j], fmaf(dy, skv, sdkv), wd);
    }
    wd *= ureg;
    wd = blk_sum(wd, red);

    if (tid == 0) {
        parts[img * 3 + 0] = loss;
        parts[img * 3 + 1] = wd;
        parts[img * 3 + 2] = ot;
    }
}

__global__ void ot_sum(const float* __restrict__ parts, float* __restrict__ out)
{
    int t = threadIdx.x;
    if (t < 3) {
        float s = 0.f;
        for (int i = 0; i < N_IMG; ++i) s += parts[i * 3 + t];
        out[t] = s;
    }
}

// ---------------------------------------------------------------- launch ---
extern "C" void kernel_launch(void* const* d_in, const int* in_sizes, int n_in,
                              void* d_out, int out_size, void* d_ws, size_t ws_size,
                              hipStream_t stream_)
{
    const float* nd  = (const float*)d_in[0];   // normed_density  [8][16384]
    const float* und = (const float*)d_in[1];   // unnormed_density[8][16384]
    const float* pts = (const float*)d_in[2];   // points          [8][1024][2]

    char* ws = (char*)d_ws;
    uint4*  kxs     = (uint4*)ws;                         // 8*32768*16 = 4MB
    uint4*  kys     = (uint4*)(ws + 4194304);             // 4MB
    u16*    pstream = (u16*)(ws + 8388608);               // 512KB
    u16*    tileofg = (u16*)(ws + 8912896);               // 16KB
    uint_t* cbaseg  = (uint_t*)(ws + 8929280);            // 512B
    uint_t* cleng   = (uint_t*)(ws + 8929792);            // 512B
    float*  parts   = (float*)(ws + 8930304);             // 96B
    // total < 9MB

    hipMemsetAsync(kxs, 0, 8388608, stream_);             // zero coeff pads
    ot_build<<<N_IMG, 1024, 0, stream_>>>(pts, kxs, kys, pstream, tileofg, cbaseg, cleng);
    ot_fused<<<N_IMG, 1024, 0, stream_>>>(nd, und, pts, kxs, kys, pstream, tileofg,
                                          cbaseg, cleng, parts);
    ot_sum<<<1, 64, 0, stream_>>>(parts, (float*)d_out);
}

// Round 12
// 703.080 us; speedup vs baseline: 1.1315x; 1.1315x over previous
//
#include <hip/hip_runtime.h>

// Fused OT Sinkhorn, MI355X — round 12: round-10 phase A (16B bf16 packed
// entries, latency-balanced) + round-11 dot2 phase B.
// Round-11 post-mortem: f32 coeff split doubled phase-A stream bytes and
// thinned the loop body to ~12 VALU -> latency-bound (VALUBusy fell 2.56->
// 1.46 while time rose). Phase B dot2 is innocent (no memory-pattern change,
// correct on HW). Hybrid: revert A, keep B.

#define N_IMG   8
#define N_PTS   1024
#define OUT_D   128
#define N_CELLS (OUT_D * OUT_D)
#define WIN     11
#define RT      5
#define WINX    18
#define N_TILE  1024            // 32x32 tiles of 4x4 cells
#define N_CHUNK 16
#define CAPE    32768           // stream entries per image (slack; ~15K used)
#define EPS     1e-16f
#define INV_N   (1.0f / 1024.0f)
#define N_ITERS 100

typedef unsigned int   uint_t;
typedef unsigned short u16;
typedef float v2f __attribute__((ext_vector_type(2)));

__device__ __forceinline__ u16 f2bf(float f) {      // RNE f32->bf16
    uint_t b = __float_as_uint(f);
    b += 0x7FFFu + ((b >> 16) & 1u);
    return (u16)(b >> 16);
}
__device__ __forceinline__ float bf2f(u16 h)   { return __uint_as_float(((uint_t)h) << 16); }
__device__ __forceinline__ float bflo(uint_t w){ return __uint_as_float(w << 16); }
__device__ __forceinline__ float bfhi(uint_t w){ return __uint_as_float(w & 0xFFFF0000u); }
__device__ __forceinline__ uint_t cvt_pk_bf16(float lo, float hi) {
    uint_t r;
    asm volatile("v_cvt_pk_bf16_f32 %0, %1, %2" : "=v"(r) : "v"(lo), "v"(hi));
    return r;
}
__device__ __forceinline__ float dot2bf(uint_t a, uint_t b, float c) {
    float r;
    asm volatile("v_dot2_f32_bf16 %0, %1, %2, %3" : "=v"(r) : "v"(a), "v"(b), "v"(c));
    return r;
}

// ---------------------------------------------------------------- builder --
// One WG per image. Deterministic entry positions (no heavy atomics):
// tile list order = (iy0 asc, ix0 asc, pid asc) via row-prefix table P.
__global__ __launch_bounds__(1024) void ot_build(
    const float* __restrict__ pts, uint4* __restrict__ cstream,
    u16* __restrict__ pstream, u16* __restrict__ tileofg,
    uint_t* __restrict__ cbaseg, uint_t* __restrict__ cleng)
{
    __shared__ uint_t chist[N_CELLS];      // 64KB
    __shared__ u16    P[128 * 129];        // 33KB  P[r][c] = #pts row r, ix0 < c
    __shared__ u16    c0tab[N_PTS];
    __shared__ u16    tslot[N_TILE];
    __shared__ u16    tlen[N_TILE];
    __shared__ u16    tof[N_TILE];
    __shared__ uint_t bins[1025];
    __shared__ uint_t cbase_l[N_CHUNK + 1];

    const int img = blockIdx.x, tid = threadIdx.x;
    for (int i = tid; i < N_CELLS; i += 1024) chist[i] = 0;
    for (int i = tid; i < 1025;    i += 1024) bins[i] = 0;
    __syncthreads();

    const float x = pts[(img * N_PTS + tid) * 2 + 0];
    const float y = pts[(img * N_PTS + tid) * 2 + 1];
    const int nx = (int)floorf((x - 2.f) * 0.25f + 0.5f);
    const int ny = (int)floorf((y - 2.f) * 0.25f + 0.5f);
    const int ix0 = min(max(nx - RT, 0), OUT_D - WIN);
    const int iy0 = min(max(ny - RT, 0), OUT_D - WIN);
    const float xx = x * x, yy = y * y;
    float kx[WIN], ky[WIN];
#pragma unroll
    for (int k = 0; k < WIN; ++k) {        // mimic reference's x^2-2xc+c^2
        float cx = (float)(4 * (ix0 + k) + 2);
        kx[k] = __expf(-((xx - 2.f * x * cx) + cx * cx) * 0.1f);
        float cy = (float)(4 * (iy0 + k) + 2);
        ky[k] = __expf(-((yy - 2.f * y * cy) + cy * cy) * 0.1f);
    }
    const int cell0 = (iy0 << 7) | ix0;
    c0tab[tid] = (u16)cell0;
    atomicAdd(&chist[cell0], 1u);
    __syncthreads();

    if (tid < 128) {
        uint_t acc = 0;
        P[tid * 129 + 0] = 0;
        for (int c = 0; c < 128; ++c) { acc += chist[(tid << 7) + c]; P[tid * 129 + c + 1] = (u16)acc; }
    }
    __syncthreads();

    int rank = 0;                          // among same-(iy0,ix0), by pid
    for (int p = 0; p < N_PTS; ++p) rank += (p < tid && c0tab[p] == (u16)cell0) ? 1 : 0;

    // tile lengths (thread = tile) + length histogram
    {
        int ty = tid >> 5, tx = tid & 31;
        int rlo = max(4 * ty - 10, 0), rhi = min(4 * ty + 3, OUT_D - WIN);
        int xlo = max(4 * tx - 10, 0), xhi = min(4 * tx + 3, OUT_D - WIN);
        uint_t len = 0;
        for (int r = rlo; r <= rhi; ++r)
            len += (uint_t)P[r * 129 + xhi + 1] - (uint_t)P[r * 129 + xlo];
        tlen[tid] = (u16)len;
        atomicAdd(&bins[len], 1u);
    }
    __syncthreads();
    if (tid == 0) {                        // descending-length start offsets
        uint_t acc = 0;
        for (int L = 1024; L >= 0; --L) { uint_t t = bins[L]; bins[L] = acc; acc += t; }
    }
    __syncthreads();
    {
        uint_t slot = atomicAdd(&bins[tlen[tid]], 1u);
        tslot[tid] = (u16)slot;
        tof[slot] = (u16)tid;
    }
    __syncthreads();
    if (tid < N_CHUNK) cbase_l[tid] = tlen[tof[tid * 64]];   // chunk maxlen
    __syncthreads();
    if (tid == 0) {
        uint_t acc = 0;
        for (int c = 0; c < N_CHUNK; ++c) { uint_t l = cbase_l[c]; cbase_l[c] = acc; acc += l * 64u; }
        cbase_l[N_CHUNK] = acc;
    }
    __syncthreads();
    tileofg[img * N_TILE + tid] = tof[tid];
    if (tid < N_CHUNK) {
        cbaseg[img * N_CHUNK + tid] = cbase_l[tid];
        cleng[img * N_CHUNK + tid]  = tlen[tof[tid * 64]];
    }

    // fill streams (packed bf16 coefficients, 16B/entry)
    uint4* cs = cstream + (size_t)img * CAPE;
    u16*   ps = pstream + (size_t)img * CAPE;
    const int tya = iy0 >> 2, tyb = (iy0 + 10) >> 2;
    const int txa = ix0 >> 2, txb = (ix0 + 10) >> 2;
    for (int ty = tya; ty <= tyb; ++ty) {
        for (int tx = txa; tx <= txb; ++tx) {
            int ti = (ty << 5) | tx;
            int slot = tslot[ti];
            int xlo = max(4 * tx - 10, 0), xhi = min(4 * tx + 3, OUT_D - WIN);
            int rlo = max(4 * ty - 10, 0);
            uint_t idx = (uint_t)rank + (uint_t)P[iy0 * 129 + ix0] - (uint_t)P[iy0 * 129 + xlo];
            for (int r = rlo; r < iy0; ++r)
                idx += (uint_t)P[r * 129 + xhi + 1] - (uint_t)P[r * 129 + xlo];
            uint_t eofs = cbase_l[slot >> 6] + idx * 64u + (uint_t)(slot & 63);
            if (eofs < CAPE) {
                u16 kxp[4], kyp[4];
#pragma unroll
                for (int c = 0; c < 4; ++c) {
                    int dk = 4 * tx + c - ix0;
                    kxp[c] = ((unsigned)dk < 11u) ? f2bf(kx[dk]) : (u16)0;
                    int dj = 4 * ty + c - iy0;
                    kyp[c] = ((unsigned)dj < 11u) ? f2bf(ky[dj]) : (u16)0;
                }
                cs[eofs] = make_uint4((uint_t)kxp[0] | ((uint_t)kxp[1] << 16),
                                      (uint_t)kxp[2] | ((uint_t)kxp[3] << 16),
                                      (uint_t)kyp[0] | ((uint_t)kyp[1] << 16),
                                      (uint_t)kyp[2] | ((uint_t)kyp[3] << 16));
                ps[eofs] = (u16)tid;
            }
        }
    }
}

// ------------------------------------------------------------ main kernel --
__device__ __forceinline__ float blk_sum(float v, volatile float* red)
{
#pragma unroll
    for (int o = 32; o; o >>= 1) v += __shfl_xor(v, o, 64);
    int wave = threadIdx.x >> 6, lane = threadIdx.x & 63;
    if (lane == 0) red[wave] = v;
    __syncthreads();
    if (threadIdx.x < 64) {
        float t = (lane < 16) ? red[lane] : 0.0f;
#pragma unroll
        for (int o = 8; o; o >>= 1) t += __shfl_xor(t, o, 64);
        if (lane == 0) red[0] = t;
    }
    __syncthreads();
    float r = red[0];
    __syncthreads();
    return r;
}

__global__ __launch_bounds__(1024) void ot_fused(
    const float* __restrict__ nd, const float* __restrict__ und,
    const float* __restrict__ pts, const uint4* __restrict__ cstream,
    const u16* __restrict__ pstream, const u16* __restrict__ tileofg,
    const uint_t* __restrict__ cbaseg, const uint_t* __restrict__ cleng,
    float* __restrict__ parts)
{
    __shared__ __align__(16) u16 Vh[N_CELLS + 32]; // 32KB bf16 v + zero-mul pad
    __shared__ float  su[N_PTS];                   // 4KB
    __shared__ u16    bktab[N_PTS];                // point -> bank group
    __shared__ u16    sorted_pt[N_PTS];            // deal: slot -> pid
    __shared__ u16    leftover[N_PTS];             // leftover rank -> pid
    __shared__ uint_t ng[8];                       // bucket counts
    __shared__ uint_t og[8];                       // overfull prefix
    __shared__ uint_t cbase_l[N_CHUNK];
    __shared__ uint_t clen_l[N_CHUNK];
    __shared__ float  red[64];

    const int img = blockIdx.x, tid = threadIdx.x;
    const int w = tid >> 6, lane = tid & 63;
    const float* ndi = nd + img * N_CELLS;

    if (tid < N_CHUNK) { cbase_l[tid] = cbaseg[img * N_CHUNK + tid]; clen_l[tid] = cleng[img * N_CHUNK + tid]; }
    if (tid < 32) Vh[N_CELLS + tid] = 0;
    if (tid < 8)  ng[tid] = 0;
    su[tid] = INV_N;
    __syncthreads();

    // ---- exact cluster-aligned deal (bf16 bank geometry) ------------------
    {
        float x_ = pts[(img * N_PTS + tid) * 2 + 0];
        int nx_ = (int)floorf((x_ - 2.f) * 0.25f + 0.5f);
        int i0_ = min(max(nx_ - RT, 0), OUT_D - WIN);
        bktab[tid] = (u16)(((i0_ & ~7) >> 3) & 7);
    }
    __syncthreads();
    {
        const int g = (int)bktab[tid];
        int rnk = 0;                       // deterministic rank by pid
        for (int p = 0; p < tid; ++p) rnk += ((int)bktab[p] == g) ? 1 : 0;
        atomicAdd(&ng[g], 1u);
        __syncthreads();
        if (tid == 0) {
            uint_t acc = 0;
            for (int b = 0; b < 8; ++b) { og[b] = acc; acc += (ng[b] > 128u) ? ng[b] - 128u : 0u; }
        }
        __syncthreads();
        if (rnk < 128) sorted_pt[rnk * 8 + g] = (u16)tid;        // cluster rnk, slot g
        else           leftover[og[g] + (uint_t)(rnk - 128)] = (u16)tid;
        __syncthreads();
        const int c = tid >> 3, j = tid & 7;                     // my slot
        if (c >= (int)ng[j]) {             // empty slot -> take E-th leftover
            int E = 0;
#pragma unroll
            for (int j2 = 0; j2 < 8; ++j2) {
                int nj = (int)ng[j2];
                E += max(0, c - nj) + ((j2 < j && c >= nj) ? 1 : 0);
            }
            sorted_pt[tid] = leftover[E];
        }
    }
    __syncthreads();
    const int pp = (int)sorted_pt[tid];    // my point (cluster-bank-tiled)

    // ---- phase-A ownership: thread owns one 4x4 tile (slot = w*64+lane) ---
    const int tile = (int)tileofg[img * N_TILE + w * 64 + lane];
    const int ty4 = (tile >> 5) * 4, tx4 = (tile & 31) * 4;
    float4 b4[4];
#pragma unroll
    for (int r = 0; r < 4; ++r) b4[r] = *(const float4*)(ndi + (ty4 + r) * OUT_D + tx4);
    const uint4* csb = cstream + (size_t)img * CAPE + cbase_l[w] + lane;
    const u16*   psb = pstream + (size_t)img * CAPE + cbase_l[w] + lane;
    const int    alen = (int)clen_l[w];               // wave-uniform

    // ---- phase-B per-point data (thread = point pp) -----------------------
    const float x = pts[(img * N_PTS + pp) * 2 + 0];
    const float y = pts[(img * N_PTS + pp) * 2 + 1];
    const int nx = (int)floorf((x - 2.f) * 0.25f + 0.5f);
    const int ny = (int)floorf((y - 2.f) * 0.25f + 0.5f);
    const int ix0 = min(max(nx - RT, 0), OUT_D - WIN);
    const int iy0 = min(max(ny - RT, 0), OUT_D - WIN);
    const int ixq = ix0 & ~7;                          // 16B-aligned bf16 window
    const float xx = x * x, yy = y * y;
    uint_t kxp[WINX / 2];                              // 9 packed bf16 pairs
    float  kyr[WIN];
#pragma unroll
    for (int q = 0; q < WINX / 2; ++q) {
        float kv[2];
#pragma unroll
        for (int h = 0; h < 2; ++h) {
            int col = ixq + 2 * q + h, dk = col - ix0;
            float cx = (float)(4 * col + 2);
            kv[h] = ((unsigned)dk < 11u) ? __expf(-((xx - 2.f * x * cx) + cx * cx) * 0.1f) : 0.f;
        }
        kxp[q] = cvt_pk_bf16(kv[0], kv[1]);
    }
#pragma unroll
    for (int j = 0; j < WIN; ++j) {
        float cy = (float)(4 * (iy0 + j) + 2);
        kyr[j] = __expf(-((yy - 2.f * y * cy) + cy * cy) * 0.1f);
    }
    float ureg = INV_N;
    const u16* vbp = &Vh[iy0 * OUT_D + ixq];

    // ---- Sinkhorn main loop ----------------------------------------------
    for (int it = 0; it < N_ITERS; ++it) {
        // phase A: 4x4-tile gather, prefetch-1, packed bf16 entry (round 10)
        v2f acc2[8] = {};
        uint4 cw = make_uint4(0u, 0u, 0u, 0u); u16 pid = 0;
        if (alen > 0) { cw = csb[0]; pid = psb[0]; }
        for (int t = 1; t <= alen; ++t) {
            uint4 cwn = csb[(size_t)t * 64];          // prefetch (pads zeroed,
            u16   pn  = psb[(size_t)t * 64];          //  CAPE has slack)
            float uv = su[pid & 1023u];
            v2f kxa = {bflo(cw.x), bfhi(cw.x)};
            v2f kxb = {bflo(cw.y), bfhi(cw.y)};
            float u0 = uv * bflo(cw.z), u1 = uv * bfhi(cw.z);
            float u2 = uv * bflo(cw.w), u3 = uv * bfhi(cw.w);
            v2f s0 = {u0, u0}, s1 = {u1, u1}, s2 = {u2, u2}, s3 = {u3, u3};
            acc2[0] += s0 * kxa;  acc2[1] += s0 * kxb;
            acc2[2] += s1 * kxa;  acc2[3] += s1 * kxb;
            acc2[4] += s2 * kxa;  acc2[5] += s2 * kxb;
            acc2[6] += s3 * kxa;  acc2[7] += s3 * kxb;
            cw = cwn; pid = pn;
        }
#pragma unroll
        for (int r = 0; r < 4; ++r) {                 // v = b*rcp(S+eps), pack
            float v0 = b4[r].x * __builtin_amdgcn_rcpf(acc2[2 * r][0] + EPS);
            float v1 = b4[r].y * __builtin_amdgcn_rcpf(acc2[2 * r][1] + EPS);
            float v2 = b4[r].z * __builtin_amdgcn_rcpf(acc2[2 * r + 1][0] + EPS);
            float v3 = b4[r].w * __builtin_amdgcn_rcpf(acc2[2 * r + 1][1] + EPS);
            uint2 wv = make_uint2(cvt_pk_bf16(v0, v1), cvt_pk_bf16(v2, v3));
            *(uint2*)&Vh[(ty4 + r) * OUT_D + tx4] = wv;   // 8B, 8B-aligned
        }
        __syncthreads();

        // phase B: 18-wide bf16 rows, 2x b128 + 1x b32, 9 dot2 per row
        float tt = 0.f;
#pragma unroll
        for (int j = 0; j < WIN; ++j) {
            const u16* row = vbp + j * OUT_D;
            uint4 w0 = *(const uint4*)(row);          // cols 0..7
            uint4 w1 = *(const uint4*)(row + 8);      // cols 8..15
            uint_t w2 = *(const uint_t*)(row + 16);   // cols 16..17
            float rs0, rs1;                           // 2 chains
            rs0 = dot2bf(kxp[0], w0.x, 0.f);
            rs1 = dot2bf(kxp[1], w0.y, 0.f);
            rs0 = dot2bf(kxp[2], w0.z, rs0);
            rs1 = dot2bf(kxp[3], w0.w, rs1);
            rs0 = dot2bf(kxp[4], w1.x, rs0);
            rs1 = dot2bf(kxp[5], w1.y, rs1);
            rs0 = dot2bf(kxp[6], w1.z, rs0);
            rs1 = dot2bf(kxp[7], w1.w, rs1);
            rs0 = dot2bf(kxp[8], w2,   rs0);
            tt = fmaf(kyr[j], rs0 + rs1, tt);
        }
        ureg = INV_N / (tt + EPS);
        su[pp] = ureg;
        __syncthreads();
    }

    // ---- epilogue ---------------------------------------------------------
    const float* sdi = und + img * N_CELLS;
    float sc = 0.f, T = 0.f, ot = 0.f;
#pragma unroll
    for (int r = 0; r < 16; ++r) {
        int c = r * 1024 + tid;
        float beta = 10.0f * logf(bf2f(Vh[c]) + EPS);
        float s = sdi[c];
        sc += s;
        T  = fmaf(s, beta, T);
        ot = fmaf(ndi[c], beta, ot);
    }
    sc = blk_sum(sc, red);
    T  = blk_sum(T,  red);
    ot = blk_sum(ot, red);
    float denom = sc * sc + 1e-8f;
    float c1 = sc / denom, c2 = T / denom;

    float loss = 0.f;
#pragma unroll
    for (int r = 0; r < 16; ++r) {
        int c = r * 1024 + tid;
        float beta = 10.0f * logf(bf2f(Vh[c]) + EPS);
        loss = fmaf(sdi[c], fmaf(c1, beta, -c2), loss);
    }
    loss = blk_sum(loss, red);

    // wd = u_n * sum_window (dy+dx)*Ky*Kx*v (18-tap x-window, kx=0 off-window)
    float wd = 0.f;
#pragma unroll
    for (int j = 0; j < WIN; ++j) {
        float cy = (float)(4 * (iy0 + j) + 2);
        float dy = (yy - 2.f * y * cy) + cy * cy;
        const u16* row = vbp + j * OUT_D;
        float skv = 0.f, sdkv = 0.f;
#pragma unroll
        for (int d = 0; d < WINX; ++d) {
            int col = ixq + d, dk = col - ix0;
            float cx = (float)(4 * col + 2);
            float kxv = ((unsigned)dk < 11u) ? __expf(-((xx - 2.f * x * cx) + cx * cx) * 0.1f) : 0.f;
            float dx = (xx - 2.f * x * cx) + cx * cx;
            float kv = kxv * bf2f(row[d]);
            skv += kv;
            sdkv = fmaf(dx, kv, sdkv);
        }
        wd = fmaf(kyr[j], fmaf(dy, skv, sdkv), wd);
    }
    wd *= ureg;
    wd = blk_sum(wd, red);

    if (tid == 0) {
        parts[img * 3 + 0] = loss;
        parts[img * 3 + 1] = wd;
        parts[img * 3 + 2] = ot;
    }
}

__global__ void ot_sum(const float* __restrict__ parts, float* __restrict__ out)
{
    int t = threadIdx.x;
    if (t < 3) {
        float s = 0.f;
        for (int i = 0; i < N_IMG; ++i) s += parts[i * 3 + t];
        out[t] = s;
    }
}

// ---------------------------------------------------------------- launch ---
extern "C" void kernel_launch(void* const* d_in, const int* in_sizes, int n_in,
                              void* d_out, int out_size, void* d_ws, size_t ws_size,
                              hipStream_t stream_)
{
    const float* nd  = (const float*)d_in[0];   // normed_density  [8][16384]
    const float* und = (const float*)d_in[1];   // unnormed_density[8][16384]
    const float* pts = (const float*)d_in[2];   // points          [8][1024][2]

    char* ws = (char*)d_ws;
    uint4*  cstream = (uint4*)ws;                         // 8*32768*16 = 4MB
    u16*    pstream = (u16*)(ws + 4194304);               // 512KB
    u16*    tileofg = (u16*)(ws + 4718592);               // 16KB
    uint_t* cbaseg  = (uint_t*)(ws + 4734976);            // 512B
    uint_t* cleng   = (uint_t*)(ws + 4735488);            // 512B
    float*  parts   = (float*)(ws + 4736000);             // 96B
    // total < 5MB

    hipMemsetAsync(cstream, 0, 4194304, stream_);         // zero coeff pads
    ot_build<<<N_IMG, 1024, 0, stream_>>>(pts, cstream, pstream, tileofg, cbaseg, cleng);
    ot_fused<<<N_IMG, 1024, 0, stream_>>>(nd, und, pts, cstream, pstream, tileofg,
                                          cbaseg, cleng, parts);
    ot_sum<<<1, 64, 0, stream_>>>(parts, (float*)d_out);
}